// Round 2
// baseline (705.135 us; speedup 1.0000x reference)
//
#include <hip/hip_runtime.h>

typedef __attribute__((ext_vector_type(8))) short bf16x8;
typedef __attribute__((ext_vector_type(4))) float floatx4;
typedef __attribute__((ext_vector_type(4))) unsigned int uintx4;

#define EPSF 1e-5f
#define RS512 0.04419417382415922f /* 1/sqrt(512) */

__device__ __forceinline__ unsigned short f2bf(float f) {
  unsigned int u = __float_as_uint(f);
  u += 0x7fffu + ((u >> 16) & 1u);
  return (unsigned short)(u >> 16);
}

union BFrag { bf16x8 v; int i[4]; unsigned short s[8]; };

// async global -> LDS, 16B per lane. LDS dest must be wave-uniform base;
// global src is per-lane (this is what lets us swizzle V's placement).
__device__ __forceinline__ void gll16(const void* g, void* l) {
  __builtin_amdgcn_global_load_lds(
      (__attribute__((address_space(1))) void*)g,
      (__attribute__((address_space(3))) void*)l, 16, 0, 0);
}

// ---------------- Kernel 1: fused qkv conv + BN + PReLU, bf16 emit ----------
// 512 threads (8 waves): LDS caps at 2 blocks/CU -> 4 waves/SIMD (was 2).
// Q: [8][4000][512] token-major; K: same (pre-scaled 1/sqrt(512));
// V: tiled [8][125][512][32].
__global__ __launch_bounds__(512) void qkv_kernel(
    const float* __restrict__ x,
    const float* __restrict__ Wq, const float* __restrict__ bq,
    const float* __restrict__ gq, const float* __restrict__ beq,
    const float* __restrict__ mq, const float* __restrict__ vq,
    const float* __restrict__ aq,
    unsigned short* __restrict__ Q, unsigned short* __restrict__ K,
    unsigned short* __restrict__ V) {
  const int b = blockIdx.y;
  const int t0 = blockIdx.x << 4;  // 250 blocks: t0 in [0,4000)
  const int tid = threadIdx.x;

  // xs pitch 1032 shorts (2064 B = 129*16): keeps b128 compute reads aligned
  // and bank-spread (129 odd in 16B quads).
  __shared__ unsigned short xs[16 * 1032];  // [lt][i*32+f] bf16 (~33 KB)
  __shared__ float sW[1536];                // folded qkv weights
  __shared__ float sB[48];                  // folded qkv biases
  __shared__ unsigned short vsm[512 * 18];  // V transpose staging (18 KB)

  // fold BN into conv weights/bias (K additionally scaled by 1/sqrt(512))
  for (int idx = tid; idx < 1536; idx += 512) {
    int n = idx >> 9, ch = (idx >> 5) & 15;
    float inv = gq[n * 16 + ch] * rsqrtf(vq[n * 16 + ch] + EPSF);
    if (n == 1) inv *= RS512;
    sW[idx] = Wq[idx] * inv;
  }
  if (tid < 48) {
    int n = tid >> 4;
    float inv = gq[tid] * rsqrtf(vq[tid] + EPSF);
    float bb = (bq[tid] - mq[tid]) * inv + beq[tid];
    if (n == 1) bb *= RS512;
    sB[tid] = bb;
  }
  {  // stage x[b,:,:,t0..t0+15] into LDS, t-major, bf16 — float4 vectorized
    int tq = tid & 3, rq = tid >> 2;
    const float* xb = x + (size_t)b * 1024 * 4000 + t0 + (tq << 2);
    for (int rr = rq; rr < 1024; rr += 128) {
      float4 f = *(const float4*)(xb + (size_t)rr * 4000);
      xs[(tq * 4 + 0) * 1032 + rr] = f2bf(f.x);
      xs[(tq * 4 + 1) * 1032 + rr] = f2bf(f.y);
      xs[(tq * 4 + 2) * 1032 + rr] = f2bf(f.z);
      xs[(tq * 4 + 3) * 1032 + rr] = f2bf(f.w);
    }
  }
  __syncthreads();

  const int lane = tid & 63, w = tid >> 6;
  const int c = lane & 15, qd = lane >> 4;
  const int wg = w >> 2;            // wave-group: 0 -> ch 0-7, 1 -> ch 8-15
  const int lt = (w & 3) * 4 + qd;  // 16 lt covered per wave-group
  const int t = t0 + lt;
  const int f0 = (c & 3) * 8;
  const unsigned short* xrow = xs + lt * 1032;
  const float aQ = aq[0], aK = aq[1], aV = aq[2];

  for (int p = 0; p < 2; ++p) {
    const int pp = p + (wg << 1);
    const int ch = (c >> 2) + (pp << 2);
    float acq[8], ack[8], acv[8];
#pragma unroll
    for (int j = 0; j < 8; ++j) {
      acq[j] = sB[ch]; ack[j] = sB[16 + ch]; acv[j] = sB[32 + ch];
    }
    const float* wqp = sW + ch * 32;
    const float* wkp = sW + 512 + ch * 32;
    const float* wvp = sW + 1024 + ch * 32;
    for (int i = 0; i < 32; ++i) {
      BFrag xf;
      xf.v = *(const bf16x8*)(xrow + i * 32 + f0);
      float wqi = wqp[i], wki = wkp[i], wvi2 = wvp[i];
#pragma unroll
      for (int j = 0; j < 8; ++j) {
        float xv = __uint_as_float((unsigned int)xf.s[j] << 16);
        acq[j] += wqi * xv; ack[j] += wki * xv; acv[j] += wvi2 * xv;
      }
    }
    // PReLU + pack + store Q,K (16B coalesced); V via LDS transpose
    unsigned int qw[4], kw[4];
#pragma unroll
    for (int j2 = 0; j2 < 4; ++j2) {
      float q0 = acq[2 * j2], q1 = acq[2 * j2 + 1];
      q0 = q0 > 0.f ? q0 : aQ * q0; q1 = q1 > 0.f ? q1 : aQ * q1;
      qw[j2] = (unsigned int)f2bf(q0) | ((unsigned int)f2bf(q1) << 16);
      float k0 = ack[2 * j2], k1 = ack[2 * j2 + 1];
      k0 = k0 > 0.f ? k0 : aK * k0; k1 = k1 > 0.f ? k1 : aK * k1;
      kw[j2] = (unsigned int)f2bf(k0) | ((unsigned int)f2bf(k1) << 16);
    }
    const int d0 = (pp << 7) + (c << 3);
    uintx4 qv, kv;
    qv[0] = qw[0]; qv[1] = qw[1]; qv[2] = qw[2]; qv[3] = qw[3];
    kv[0] = kw[0]; kv[1] = kw[1]; kv[2] = kw[2]; kv[3] = kw[3];
    *(uintx4*)(Q + (size_t)(b * 4000 + t) * 512 + d0) = qv;
    *(uintx4*)(K + (size_t)(b * 4000 + t) * 512 + d0) = kv;
#pragma unroll
    for (int j = 0; j < 8; ++j) {
      float v0 = acv[j];
      v0 = v0 > 0.f ? v0 : aV * v0;
      vsm[(d0 + j) * 18 + lt] = f2bf(v0);
    }
  }
  __syncthreads();
  {
    const int st = t0 >> 5;
    const int toff = t0 & 16;
    unsigned short* vt = V + ((size_t)(b * 125 + st) * 512) * 32 + toff;
    for (int i = tid; i < 4096; i += 512) {
      int d = i >> 3, u = i & 7;
      unsigned int w2 = *(unsigned int*)&vsm[d * 18 + 2 * u];
      ((unsigned int*)(vt + d * 32))[u] = w2;
    }
  }
}

// ---------------- Kernel 2: LDS-staged sigmoid-attention + enc ConvBlock ----
// 512 threads = 8 waves, each wave owns 16 q-tokens (block = 128 tokens).
// Sweep 125 s-tiles of 32. K/V double-buffered in LDS via global_load_lds,
// one barrier per iter. V is stored XOR-permuted at 16B-granule level:
// logical granule g -> physical g ^ ((g>>2)&7), so the per-md ds_read_b128
// hits all 8 bank-quads per 8-lane group (was 4-way conflicted when linear).
// gll dest stays linear; the permutation is applied on the global SOURCE
// address (guide rule #21) and on the read address (per-lane constant).
__global__ __launch_bounds__(512, 2) void attn_kernel(
    const float* __restrict__ x,
    const float* __restrict__ encW, const float* __restrict__ encb,
    const float* __restrict__ encg, const float* __restrict__ encbe,
    const float* __restrict__ encm, const float* __restrict__ encv,
    const float* __restrict__ enca,
    const unsigned short* __restrict__ Q, const unsigned short* __restrict__ K,
    const unsigned short* __restrict__ V, float* __restrict__ out) {
  const int tid = threadIdx.x;
  const int lane = tid & 63;
  const int w = tid >> 6;
  const int b = blockIdx.x >> 5;           // 8 b * 32 blocks
  const int bt0 = (blockIdx.x & 31) << 7;  // 0..3968
  const int t0 = bt0 + (w << 4);
  const bool active = t0 < 4000;
  const int c = lane & 15, qd = lane >> 4;

  __shared__ unsigned short Ks[2][32 * 520];  // K rows padded to 1040 B
  __shared__ unsigned short Vs[2][512 * 32];  // granule-permuted (see above)

  // Q fragments for this wave's 16 tokens (B operand of S-mfma)
  bf16x8 qf[16];
  {
    const int tq = active ? t0 : 0;
    const unsigned short* qp = Q + (size_t)(b * 4000 + tq + c) * 512 + qd * 8;
#pragma unroll
    for (int ks = 0; ks < 16; ++ks) qf[ks] = *(const bf16x8*)(qp + ks * 32);
  }

  floatx4 acc[32];
#pragma unroll
  for (int md = 0; md < 32; ++md) {
    acc[md][0] = 0.f; acc[md][1] = 0.f; acc[md][2] = 0.f; acc[md][3] = 0.f;
  }

  const unsigned short* Kb = K + (size_t)b * 4000 * 512;
  const unsigned short* Vb = V + (size_t)b * 125 * 16384;
  const int srcA = ((((qd << 1) & 3) << 4) | c) << 2;  // bpermute byte index
  const int srcB = srcA + 64;

  // wave w stages K rows 4w..4w+3 (1024 B each) and V chunks 4w..4w+3
  const int r0 = w << 2;
  const int lby = lane * 8;  // 16B per lane, in shorts
  // V source swizzle: physical granule l sources logical granule
  // l ^ (((l>>2)&7) ^ ((l>>4)&1))  — exact inverse of the read-side map.
  const int vmask = ((lane >> 2) & 7) ^ ((lane >> 4) & 1);
  const int vsw = (lane ^ vmask) << 3;  // shorts within 1024B chunk

  auto stage = [&](int buf, int it) {
    const unsigned short* kg = Kb + (size_t)it * 32 * 512;
    const unsigned short* vg = Vb + (size_t)it * 16384;
#pragma unroll
    for (int r = 0; r < 4; ++r) {
      gll16(kg + (size_t)(r0 + r) * 512 + lby, &Ks[buf][(r0 + r) * 520]);
      gll16(vg + (size_t)(r0 + r) * 512 + vsw, &Vs[buf][(r0 + r) * 512]);
    }
  };

  stage(0, 0);
  int cur = 0;

#pragma unroll 1
  for (int it = 0; it < 125; ++it) {
    // drain this wave's in-flight gll, then barrier: buf[cur] ready for all,
    // and all are done reading buf[cur^1] from last iter.
    asm volatile("s_waitcnt vmcnt(0)" ::: "memory");
    __syncthreads();
    if (it + 1 < 125) stage(cur ^ 1, it + 1);  // in flight across compute

    if (active) {
      floatx4 sa0, sa1;
      sa0[0] = sa0[1] = sa0[2] = sa0[3] = 0.f;
      sa1 = sa0;
      const unsigned short* kp = &Ks[cur][c * 520 + qd * 8];
      __builtin_amdgcn_s_setprio(1);
#pragma unroll
      for (int ks = 0; ks < 16; ++ks) {
        bf16x8 k0 = *(const bf16x8*)(kp + ks * 32);
        bf16x8 k1 = *(const bf16x8*)(kp + 16 * 520 + ks * 32);
        sa0 = __builtin_amdgcn_mfma_f32_16x16x32_bf16(k0, qf[ks], sa0, 0, 0, 0);
        sa1 = __builtin_amdgcn_mfma_f32_16x16x32_bf16(k1, qf[ks], sa1, 0, 0, 0);
      }
      __builtin_amdgcn_s_setprio(0);
      // sigmoid -> packed bf16
      float p0 = __builtin_amdgcn_rcpf(1.f + __expf(-sa0[0]));
      float p1 = __builtin_amdgcn_rcpf(1.f + __expf(-sa0[1]));
      float p2 = __builtin_amdgcn_rcpf(1.f + __expf(-sa0[2]));
      float p3 = __builtin_amdgcn_rcpf(1.f + __expf(-sa0[3]));
      float p4 = __builtin_amdgcn_rcpf(1.f + __expf(-sa1[0]));
      float p5 = __builtin_amdgcn_rcpf(1.f + __expf(-sa1[1]));
      float p6 = __builtin_amdgcn_rcpf(1.f + __expf(-sa1[2]));
      float p7 = __builtin_amdgcn_rcpf(1.f + __expf(-sa1[3]));
      int w0 = (int)((unsigned int)f2bf(p0) | ((unsigned int)f2bf(p1) << 16));
      int w1 = (int)((unsigned int)f2bf(p2) | ((unsigned int)f2bf(p3) << 16));
      int w2 = (int)((unsigned int)f2bf(p4) | ((unsigned int)f2bf(p5) << 16));
      int w3 = (int)((unsigned int)f2bf(p6) | ((unsigned int)f2bf(p7) << 16));
      // redistribute C/D layout -> B-operand layout
      const bool lo = qd < 2;
      int b0a = __builtin_amdgcn_ds_bpermute(srcA, w0);
      int b0b = __builtin_amdgcn_ds_bpermute(srcA, w2);
      int b1a = __builtin_amdgcn_ds_bpermute(srcA, w1);
      int b1b = __builtin_amdgcn_ds_bpermute(srcA, w3);
      int b2a = __builtin_amdgcn_ds_bpermute(srcB, w0);
      int b2b = __builtin_amdgcn_ds_bpermute(srcB, w2);
      int b3a = __builtin_amdgcn_ds_bpermute(srcB, w1);
      int b3b = __builtin_amdgcn_ds_bpermute(srcB, w3);
      BFrag pf;
      pf.i[0] = lo ? b0a : b0b;
      pf.i[1] = lo ? b1a : b1b;
      pf.i[2] = lo ? b2a : b2b;
      pf.i[3] = lo ? b3a : b3b;

      // read-side granule map: logical (4c+qd) -> physical (4c+qd)^(c&7)
      const unsigned short* vp = &Vs[cur][((((c << 2) | qd) ^ (c & 7)) << 3)];
      __builtin_amdgcn_s_setprio(1);
#pragma unroll
      for (int md = 0; md < 32; ++md) {
        bf16x8 vf = *(const bf16x8*)(vp + md * 512);
        acc[md] = __builtin_amdgcn_mfma_f32_16x16x32_bf16(vf, pf.v, acc[md], 0, 0, 0);
      }
      __builtin_amdgcn_s_setprio(0);
    }
    cur ^= 1;
  }

  // ---- fused enc ConvBlock + residual epilogue ----
  if (active) {
    const float ealpha = enca[0];
#pragma unroll 1
    for (int o = 0; o < 32; ++o) {
      float inv = encg[o] * rsqrtf(encv[o] + EPSF);
      float bfo = (encb[o] - encm[o]) * inv + encbe[o];
      float wr[16];
#pragma unroll
      for (int i = 0; i < 16; ++i) wr[i] = encW[o * 16 + i];
#pragma unroll
      for (int hi = 0; hi < 2; ++hi) {
#pragma unroll
        for (int rr = 0; rr < 4; ++rr) {
          float e = 0.f;
#pragma unroll
          for (int i = 0; i < 16; ++i) e += wr[i] * acc[2 * i + hi][rr];
          e = e * inv + bfo;
          e = e > 0.f ? e : ealpha * e;
          int fq = (qd << 2) + rr + (hi << 4);
          size_t idx = ((size_t)((b << 5) + o) * 32 + fq) * 4000 + t0 + c;
          out[idx] = e + x[idx];
        }
      }
    }
  }
}

extern "C" void kernel_launch(void* const* d_in, const int* in_sizes, int n_in,
                              void* d_out, int out_size, void* d_ws,
                              size_t ws_size, hipStream_t stream) {
  const float* x = (const float*)d_in[0];
  unsigned short* Q = (unsigned short*)d_ws;
  unsigned short* K = Q + (size_t)8 * 4000 * 512;
  unsigned short* V = K + (size_t)8 * 4000 * 512;

  dim3 g1(250, 8);
  qkv_kernel<<<g1, 512, 0, stream>>>(
      x, (const float*)d_in[1], (const float*)d_in[2], (const float*)d_in[3],
      (const float*)d_in[4], (const float*)d_in[5], (const float*)d_in[6],
      (const float*)d_in[7], Q, K, V);

  attn_kernel<<<dim3(256), 512, 0, stream>>>(
      x, (const float*)d_in[8], (const float*)d_in[9], (const float*)d_in[10],
      (const float*)d_in[11], (const float*)d_in[12], (const float*)d_in[13],
      (const float*)d_in[14], Q, K, V, (float*)d_out);
}

// Round 3
// 641.024 us; speedup vs baseline: 1.1000x; 1.1000x over previous
//
#include <hip/hip_runtime.h>

typedef __attribute__((ext_vector_type(8))) short bf16x8;
typedef __attribute__((ext_vector_type(4))) float floatx4;
typedef __attribute__((ext_vector_type(4))) unsigned int uintx4;

#define EPSF 1e-5f
#define RS512 0.04419417382415922f /* 1/sqrt(512) */

__device__ __forceinline__ unsigned short f2bf(float f) {
  unsigned int u = __float_as_uint(f);
  u += 0x7fffu + ((u >> 16) & 1u);
  return (unsigned short)(u >> 16);
}

union BFrag { bf16x8 v; int i[4]; unsigned short s[8]; };

// async global -> LDS, 16B per lane. LDS dest is wave-uniform base + lane*16;
// global src is per-lane (lets us swizzle V's placement at the source).
__device__ __forceinline__ void gll16(const void* g, void* l) {
  __builtin_amdgcn_global_load_lds(
      (__attribute__((address_space(1))) void*)g,
      (__attribute__((address_space(3))) void*)l, 16, 0, 0);
}

// ---------------- Kernel 1: fused qkv conv + BN + PReLU, bf16 emit ----------
// Q: [8][4000][512] token-major; K: same (pre-scaled 1/sqrt(512));
// V: tiled [8][125][512][32].
__global__ __launch_bounds__(512) void qkv_kernel(
    const float* __restrict__ x,
    const float* __restrict__ Wq, const float* __restrict__ bq,
    const float* __restrict__ gq, const float* __restrict__ beq,
    const float* __restrict__ mq, const float* __restrict__ vq,
    const float* __restrict__ aq,
    unsigned short* __restrict__ Q, unsigned short* __restrict__ K,
    unsigned short* __restrict__ V) {
  const int b = blockIdx.y;
  const int t0 = blockIdx.x << 4;  // 250 blocks: t0 in [0,4000)
  const int tid = threadIdx.x;

  __shared__ unsigned short xs[16 * 1032];  // [lt][i*32+f] bf16 (~33 KB)
  // sW pitch 33: bank = (ch+i) mod 32 -> the 4 distinct ch addresses land in
  // 4 distinct banks (was: all in bank i -> 4-way b32 conflict x192/thread).
  __shared__ float sW[1584];                // folded qkv weights [n][ch][33]
  __shared__ float sB[48];                  // folded qkv biases
  __shared__ unsigned short vsm[512 * 18];  // V transpose staging (18 KB)

  for (int idx = tid; idx < 1536; idx += 512) {
    int n = idx >> 9, ch = (idx >> 5) & 15;
    float inv = gq[n * 16 + ch] * rsqrtf(vq[n * 16 + ch] + EPSF);
    if (n == 1) inv *= RS512;
    sW[n * 528 + ch * 33 + (idx & 31)] = Wq[idx] * inv;
  }
  if (tid < 48) {
    int n = tid >> 4;
    float inv = gq[tid] * rsqrtf(vq[tid] + EPSF);
    float bb = (bq[tid] - mq[tid]) * inv + beq[tid];
    if (n == 1) bb *= RS512;
    sB[tid] = bb;
  }
  {  // stage x[b,:,:,t0..t0+15] into LDS, t-major, bf16 — float4 vectorized
    int tq = tid & 3, rq = tid >> 2;
    const float* xb = x + (size_t)b * 1024 * 4000 + t0 + (tq << 2);
    for (int rr = rq; rr < 1024; rr += 128) {
      float4 f = *(const float4*)(xb + (size_t)rr * 4000);
      xs[(tq * 4 + 0) * 1032 + rr] = f2bf(f.x);
      xs[(tq * 4 + 1) * 1032 + rr] = f2bf(f.y);
      xs[(tq * 4 + 2) * 1032 + rr] = f2bf(f.z);
      xs[(tq * 4 + 3) * 1032 + rr] = f2bf(f.w);
    }
  }
  __syncthreads();

  const int lane = tid & 63, w = tid >> 6;
  const int c = lane & 15, qd = lane >> 4;
  const int wg = w >> 2;            // wave-group: 0 -> ch 0-7, 1 -> ch 8-15
  const int lt = (w & 3) * 4 + qd;  // 16 lt covered per wave-group
  const int t = t0 + lt;
  const int f0 = (c & 3) * 8;
  const unsigned short* xrow = xs + lt * 1032;
  const float aQ = aq[0], aK = aq[1], aV = aq[2];

  for (int p = 0; p < 2; ++p) {
    const int pp = p + (wg << 1);
    const int ch = (c >> 2) + (pp << 2);
    float acq[8], ack[8], acv[8];
#pragma unroll
    for (int j = 0; j < 8; ++j) {
      acq[j] = sB[ch]; ack[j] = sB[16 + ch]; acv[j] = sB[32 + ch];
    }
    const float* wqp = sW + ch * 33;
    const float* wkp = sW + 528 + ch * 33;
    const float* wvp = sW + 1056 + ch * 33;
    for (int i = 0; i < 32; ++i) {
      BFrag xf;
      xf.v = *(const bf16x8*)(xrow + i * 32 + f0);
      float wqi = wqp[i], wki = wkp[i], wvi2 = wvp[i];
#pragma unroll
      for (int j = 0; j < 8; ++j) {
        float xv = __uint_as_float((unsigned int)xf.s[j] << 16);
        acq[j] += wqi * xv; ack[j] += wki * xv; acv[j] += wvi2 * xv;
      }
    }
    unsigned int qw[4], kw[4];
#pragma unroll
    for (int j2 = 0; j2 < 4; ++j2) {
      float q0 = acq[2 * j2], q1 = acq[2 * j2 + 1];
      q0 = q0 > 0.f ? q0 : aQ * q0; q1 = q1 > 0.f ? q1 : aQ * q1;
      qw[j2] = (unsigned int)f2bf(q0) | ((unsigned int)f2bf(q1) << 16);
      float k0 = ack[2 * j2], k1 = ack[2 * j2 + 1];
      k0 = k0 > 0.f ? k0 : aK * k0; k1 = k1 > 0.f ? k1 : aK * k1;
      kw[j2] = (unsigned int)f2bf(k0) | ((unsigned int)f2bf(k1) << 16);
    }
    const int d0 = (pp << 7) + (c << 3);
    uintx4 qv, kv;
    qv[0] = qw[0]; qv[1] = qw[1]; qv[2] = qw[2]; qv[3] = qw[3];
    kv[0] = kw[0]; kv[1] = kw[1]; kv[2] = kw[2]; kv[3] = kw[3];
    *(uintx4*)(Q + (size_t)(b * 4000 + t) * 512 + d0) = qv;
    *(uintx4*)(K + (size_t)(b * 4000 + t) * 512 + d0) = kv;
#pragma unroll
    for (int j = 0; j < 8; ++j) {
      float v0 = acv[j];
      v0 = v0 > 0.f ? v0 : aV * v0;
      vsm[(d0 + j) * 18 + lt] = f2bf(v0);
    }
  }
  __syncthreads();
  {
    const int st = t0 >> 5;
    const int toff = t0 & 16;
    unsigned short* vt = V + ((size_t)(b * 125 + st) * 512) * 32 + toff;
    for (int i = tid; i < 4096; i += 512) {
      int d = i >> 3, u = i & 7;
      unsigned int w2 = *(unsigned int*)&vsm[d * 18 + 2 * u];
      ((unsigned int*)(vt + d * 32))[u] = w2;
    }
  }
}

// ---------------- Kernel 2: LDS-staged sigmoid-attention + enc ConvBlock ----
// 512 threads = 8 waves, block = 128 q-tokens, sweep 125 s-tiles of 32.
// S-phase: wave w computes S+sigmoid for its 16 q (reads K tile), writes
// P[16q x 32s] bf16 to LDS. PV-phase (d-split): wave w computes the PV for
// ALL 128 q but only d-slice [64w, 64w+64): reads P (8KB) + its V slice (4KB).
// V is thus read ONCE per block per tile (was 8x). Per-wave LDS/tile:
// 64 KB -> 45 KB. Epilogue exchanges acc (d-sliced) through LDS f32 buffer
// overlaid on the K/V buffers, then runs the original enc+residual per q-group.
__global__ __launch_bounds__(512, 2) void attn_kernel(
    const float* __restrict__ x,
    const float* __restrict__ encW, const float* __restrict__ encb,
    const float* __restrict__ encg, const float* __restrict__ encbe,
    const float* __restrict__ encm, const float* __restrict__ encv,
    const float* __restrict__ enca,
    const unsigned short* __restrict__ Q, const unsigned short* __restrict__ K,
    const unsigned short* __restrict__ V, float* __restrict__ out) {
  const int tid = threadIdx.x;
  const int lane = tid & 63;
  const int w = tid >> 6;
  const int b = blockIdx.x >> 5;           // 8 b * 32 blocks
  const int bt0 = (blockIdx.x & 31) << 7;  // 0..3968
  const int t0 = bt0 + (w << 4);
  const bool active = t0 < 4000;
  const int c = lane & 15, qd = lane >> 4;

  // LDS map: [Ks 2x33280B][Vs 2x32768B][Pb 10240B] = 142336 B.
  // Eb (f32 [64][516] = 132096 B) overlays Ks+Vs after the tile loop.
  __shared__ __align__(16) unsigned char smem[142336];
  unsigned short* Ksb = (unsigned short*)smem;   // [2][32*520] rows padded
  unsigned short* Vsb = Ksb + 2 * 16640;         // [2][512*32] granule-permuted
  unsigned short* Pb = Vsb + 2 * 16384;          // [128][40] bf16, pitch 80 B
  float* Eb = (float*)smem;                      // [64][516]

  // zero P rows once (covers q-groups of inactive tail waves)
  for (int i = tid; i < 2560; i += 512) ((unsigned int*)Pb)[i] = 0u;

  // Q fragments for this wave's 16 tokens (B operand of S-mfma)
  bf16x8 qf[16];
  {
    const int tq = active ? t0 : 0;
    const unsigned short* qp = Q + (size_t)(b * 4000 + tq + c) * 512 + qd * 8;
#pragma unroll
    for (int ks = 0; ks < 16; ++ks) qf[ks] = *(const bf16x8*)(qp + ks * 32);
  }

  floatx4 acc[4][8];  // [md within slice][q-sub]
#pragma unroll
  for (int m = 0; m < 4; ++m)
#pragma unroll
    for (int q2 = 0; q2 < 8; ++q2) {
      acc[m][q2][0] = 0.f; acc[m][q2][1] = 0.f;
      acc[m][q2][2] = 0.f; acc[m][q2][3] = 0.f;
    }

  const unsigned short* Kb = K + (size_t)b * 4000 * 512;
  const unsigned short* Vb = V + (size_t)b * 125 * 16384;

  // wave w stages K rows 4w..4w+3 (1024 B each) and V chunks 4w..4w+3
  const int r0 = w << 2;
  const int lby = lane * 8;  // 16B per lane, in shorts
  // V source swizzle (verified R1/R2): phys granule l sources logical
  // l ^ (((l>>2)&7) ^ ((l>>4)&1)); read side uses logical^((logical>>2)&7).
  const int vmask = ((lane >> 2) & 7) ^ ((lane >> 4) & 1);
  const int vsw = (lane ^ vmask) << 3;  // shorts within 1024B chunk

  auto stage = [&](int buf, int it) {
    const unsigned short* kg = Kb + (size_t)it * 16384;
    const unsigned short* vg = Vb + (size_t)it * 16384;
    unsigned short* kd = Ksb + buf * 16640;
    unsigned short* vd = Vsb + buf * 16384;
#pragma unroll
    for (int r = 0; r < 4; ++r) {
      gll16(kg + (size_t)((r0 + r) << 9) + lby, kd + (r0 + r) * 520);
      gll16(vg + (size_t)((r0 + r) << 9) + vsw, vd + ((r0 + r) << 9));
    }
  };

  stage(0, 0);
  int cur = 0;

#pragma unroll 1
  for (int it = 0; it < 125; ++it) {
    // drain this wave's gll, then barrier: buf[cur] staged for everyone, and
    // everyone finished last iter's PV (P and prev LDS reads done).
    asm volatile("s_waitcnt vmcnt(0)" ::: "memory");
    __syncthreads();
    if (it + 1 < 125) stage(cur ^ 1, it + 1);  // in flight across compute

    if (active) {  // ---- S-phase: S = K·Q^T for own 16 q, full 32 s ----
      floatx4 sa0, sa1;
      sa0[0] = sa0[1] = sa0[2] = sa0[3] = 0.f;
      sa1 = sa0;
      const unsigned short* kp = Ksb + cur * 16640 + c * 520 + qd * 8;
      __builtin_amdgcn_s_setprio(1);
#pragma unroll
      for (int ks = 0; ks < 16; ++ks) {
        bf16x8 k0 = *(const bf16x8*)(kp + ks * 32);
        bf16x8 k1 = *(const bf16x8*)(kp + 16 * 520 + ks * 32);
        sa0 = __builtin_amdgcn_mfma_f32_16x16x32_bf16(k0, qf[ks], sa0, 0, 0, 0);
        sa1 = __builtin_amdgcn_mfma_f32_16x16x32_bf16(k1, qf[ks], sa1, 0, 0, 0);
      }
      __builtin_amdgcn_s_setprio(0);
      // sigmoid -> packed bf16 -> P[q = w*16+c][s] (lane holds s = qd*4+r, +16)
      float p0 = __builtin_amdgcn_rcpf(1.f + __expf(-sa0[0]));
      float p1 = __builtin_amdgcn_rcpf(1.f + __expf(-sa0[1]));
      float p2 = __builtin_amdgcn_rcpf(1.f + __expf(-sa0[2]));
      float p3 = __builtin_amdgcn_rcpf(1.f + __expf(-sa0[3]));
      float p4 = __builtin_amdgcn_rcpf(1.f + __expf(-sa1[0]));
      float p5 = __builtin_amdgcn_rcpf(1.f + __expf(-sa1[1]));
      float p6 = __builtin_amdgcn_rcpf(1.f + __expf(-sa1[2]));
      float p7 = __builtin_amdgcn_rcpf(1.f + __expf(-sa1[3]));
      unsigned short* pw = Pb + ((w << 4) + c) * 40 + (qd << 2);
      uint2 pa, pb2;
      pa.x = (unsigned int)f2bf(p0) | ((unsigned int)f2bf(p1) << 16);
      pa.y = (unsigned int)f2bf(p2) | ((unsigned int)f2bf(p3) << 16);
      pb2.x = (unsigned int)f2bf(p4) | ((unsigned int)f2bf(p5) << 16);
      pb2.y = (unsigned int)f2bf(p6) | ((unsigned int)f2bf(p7) << 16);
      *(uint2*)pw = pa;
      *(uint2*)(pw + 16) = pb2;
    }
    __syncthreads();  // P complete

    {  // ---- PV-phase (ALL waves): d-slice [64w,64w+64) for all 128 q ----
      const unsigned short* vp =
          Vsb + cur * 16384 + ((((c << 2) | qd) ^ (c & 7)) << 3);
      bf16x8 vf[4];
#pragma unroll
      for (int m = 0; m < 4; ++m)
        vf[m] = *(const bf16x8*)(vp + ((r0 + m) << 9));
      __builtin_amdgcn_s_setprio(1);
#pragma unroll
      for (int h = 0; h < 2; ++h) {
        bf16x8 pf[4];
#pragma unroll
        for (int q2 = 0; q2 < 4; ++q2)
          pf[q2] = *(const bf16x8*)(Pb + ((((h << 2) | q2) << 4) + c) * 40 +
                                    (qd << 3));
#pragma unroll
        for (int m = 0; m < 4; ++m)
#pragma unroll
          for (int q2 = 0; q2 < 4; ++q2)
            acc[m][(h << 2) | q2] = __builtin_amdgcn_mfma_f32_16x16x32_bf16(
                vf[m], pf[q2], acc[m][(h << 2) | q2], 0, 0, 0);
      }
      __builtin_amdgcn_s_setprio(0);
    }
    cur ^= 1;
  }

  __syncthreads();  // all K/V reads done -> Eb may overlay

  // ---- epilogue: exchange d-sliced acc via Eb, then enc+residual ----
  const float ealpha = enca[0];
#pragma unroll
  for (int rnd = 0; rnd < 2; ++rnd) {
    // all waves write their d-slice for q 0..63 (rnd 0) / 64..127 (rnd 1)
#pragma unroll
    for (int m = 0; m < 4; ++m)
#pragma unroll
      for (int q2 = 0; q2 < 4; ++q2)
        *(floatx4*)&Eb[((q2 << 4) + c) * 516 + (w << 6) + (m << 4) +
                       (qd << 2)] = acc[m][(rnd << 2) | q2];
    __syncthreads();
    if ((w >> 2) == rnd && active) {
      const float* er = Eb + (((w & 3) << 4) + c) * 516;
#pragma unroll
      for (int hi = 0; hi < 2; ++hi) {
        floatx4 sh[16];
#pragma unroll
        for (int i = 0; i < 16; ++i)
          sh[i] = *(const floatx4*)&er[(i << 5) + (hi << 4) + (qd << 2)];
#pragma unroll 1
        for (int o = 0; o < 32; ++o) {
          float inv = encg[o] * rsqrtf(encv[o] + EPSF);
          float bfo = (encb[o] - encm[o]) * inv + encbe[o];
          float e0 = 0.f, e1 = 0.f, e2 = 0.f, e3 = 0.f;
#pragma unroll
          for (int i = 0; i < 16; ++i) {
            float wi = encW[(o << 4) + i];
            e0 += wi * sh[i][0]; e1 += wi * sh[i][1];
            e2 += wi * sh[i][2]; e3 += wi * sh[i][3];
          }
          float ee[4] = {e0, e1, e2, e3};
#pragma unroll
          for (int rr = 0; rr < 4; ++rr) {
            float e = ee[rr] * inv + bfo;
            e = e > 0.f ? e : ealpha * e;
            int fq = (qd << 2) + rr + (hi << 4);
            size_t idx = ((size_t)((b << 5) + o) * 32 + fq) * 4000 + t0 + c;
            out[idx] = e + x[idx];
          }
        }
      }
    }
    __syncthreads();
  }
}

extern "C" void kernel_launch(void* const* d_in, const int* in_sizes, int n_in,
                              void* d_out, int out_size, void* d_ws,
                              size_t ws_size, hipStream_t stream) {
  const float* x = (const float*)d_in[0];
  unsigned short* Q = (unsigned short*)d_ws;
  unsigned short* K = Q + (size_t)8 * 4000 * 512;
  unsigned short* V = K + (size_t)8 * 4000 * 512;

  dim3 g1(250, 8);
  qkv_kernel<<<g1, 512, 0, stream>>>(
      x, (const float*)d_in[1], (const float*)d_in[2], (const float*)d_in[3],
      (const float*)d_in[4], (const float*)d_in[5], (const float*)d_in[6],
      (const float*)d_in[7], Q, K, V);

  attn_kernel<<<dim3(256), 512, 0, stream>>>(
      x, (const float*)d_in[8], (const float*)d_in[9], (const float*)d_in[10],
      (const float*)d_in[11], (const float*)d_in[12], (const float*)d_in[13],
      (const float*)d_in[14], Q, K, V, (float*)d_out);
}